// Round 20
// baseline (634.441 us; speedup 1.0000x reference)
//
#include <hip/hip_runtime.h>
#include <hip/hip_bf16.h>
#include <math.h>

// OLMoE sparse MoE block: E=32, K=4, H=2048, F=1024, T=1024 tokens.
#define NE 32
#define NK 4
#define NH 2048
#define NF 1024
#define NT 1024
#define NPAIR (NT * NK)

#define BM 192
#define BN 256     // 1 KB contiguous per weight row per wave-instruction
#define BK 64
#define MAXTILES 64

typedef __attribute__((ext_vector_type(8))) short short8;
typedef __attribute__((ext_vector_type(4))) float f32x4;

#define ASMV(s) asm volatile(s ::: "memory")
#define SCHED0() __builtin_amdgcn_sched_barrier(0)

// Workspace layout (bytes). part and ypb share OFF_YP region.
static constexpr size_t OFF_CNT = 0;
static constexpr size_t OFF_ENT = 1024;
static constexpr size_t OFF_WTK = 1024 + 32 * 1024 * 4;
static constexpr size_t OFF_TIL = 200704;
static constexpr size_t OFF_XB  = 262144;                            // bf16 [1024][2048], 4MB
static constexpr size_t OFF_ACT = OFF_XB + (size_t)NT * NH * 2;      // bf16 [4096][1024], 8MB
static constexpr size_t OFF_YP  = OFF_ACT + (size_t)NPAIR * NF * 2;
static constexpr size_t OFF_PART = OFF_YP;                           // bf16 [2][4096][1024], 16MB
static constexpr size_t OFF_YPB  = OFF_YP + (size_t)2 * NPAIR * NF * 2;  // bf16 [4096][2048], 16MB

// ---------------------------------------------------------------------------
__device__ inline unsigned bfbits(float f) {
  return (unsigned)__builtin_bit_cast(unsigned short, __float2bfloat16(f));
}
__device__ inline unsigned pkbf(float lo, float hi) {
  return bfbits(lo) | (bfbits(hi) << 16);
}
__device__ inline float bf2f(unsigned short v) {
  unsigned u = ((unsigned)v) << 16;
  return __builtin_bit_cast(float, u);
}
// XOR-swizzled element index for a [rows][64] bf16 tile (row stride 128 B).
__device__ inline int swz(int r, int k) {
  int key = ((r & 7) ^ ((r >> 2) & 7)) & 7;
  int b = (r << 7) | (k << 1);
  return (b ^ (key << 4)) >> 1;
}

// ---------------------------------------------------------------------------
// Kernel 1: router (unchanged, validated).
// ---------------------------------------------------------------------------
__global__ __launch_bounds__(256) void router_kernel(
    const float* __restrict__ x, const float* __restrict__ gate_w,
    float* __restrict__ logits_out, int* __restrict__ cnt,
    int* __restrict__ entries, float* __restrict__ w_tk,
    unsigned short* __restrict__ xb) {
  __shared__ float xs[NH];
  __shared__ float logits_s[NE];
  const int t = blockIdx.x;
  const int tid = threadIdx.x;

  for (int i = tid; i < NH / 4; i += 256) {
    *reinterpret_cast<float4*>(&xs[i * 4]) =
        *reinterpret_cast<const float4*>(&x[(size_t)t * NH + i * 4]);
  }
  __syncthreads();

  {
    unsigned u[4];
#pragma unroll
    for (int j = 0; j < 4; ++j)
      u[j] = pkbf(xs[tid * 8 + 2 * j], xs[tid * 8 + 2 * j + 1]);
    *reinterpret_cast<uint4*>(&xb[(size_t)t * NH + tid * 8]) =
        make_uint4(u[0], u[1], u[2], u[3]);
  }

  const int wave = tid >> 6, lane = tid & 63;
  for (int ei = 0; ei < 8; ++ei) {
    const int e = wave * 8 + ei;
    const float* gw = gate_w + (size_t)e * NH;
    float s = 0.f;
    for (int h = lane; h < NH; h += 64) s += xs[h] * gw[h];
#pragma unroll
    for (int off = 32; off >= 1; off >>= 1) s += __shfl_xor(s, off, 64);
    if (lane == 0) logits_s[e] = s;
  }
  __syncthreads();

  if (wave == 0) {
    float v = (lane < NE) ? logits_s[lane] : -INFINITY;
    if (lane < NE) logits_out[(size_t)t * NE + lane] = v;
    float m = v;
#pragma unroll
    for (int off = 32; off >= 1; off >>= 1) m = fmaxf(m, __shfl_xor(m, off, 64));
    float ex = (lane < NE) ? expf(v - m) : 0.f;
    float sum = ex;
#pragma unroll
    for (int off = 32; off >= 1; off >>= 1) sum += __shfl_xor(sum, off, 64);
    float pv = (lane < NE) ? (ex / sum) : -1.f;
    for (int k = 0; k < NK; ++k) {
      float bv = pv;
      int bi = lane;
#pragma unroll
      for (int off = 32; off >= 1; off >>= 1) {
        float ov = __shfl_xor(bv, off, 64);
        int oi = __shfl_xor(bi, off, 64);
        if (ov > bv || (ov == bv && oi < bi)) { bv = ov; bi = oi; }
      }
      if (lane == 0) {
        int pos = atomicAdd(&cnt[bi], 1);
        entries[bi * NT + pos] = t * NK + k;
        w_tk[t * NK + k] = bv;
      }
      if (lane == bi) pv = -1.f;
    }
  }
}

// ---------------------------------------------------------------------------
// Kernel 1b: compact (expert, rowtile) tile table.
// ---------------------------------------------------------------------------
__global__ __launch_bounds__(64) void build_tiles(
    const int* __restrict__ cnt, int* __restrict__ tile_hdr) {
  const int lane = threadIdx.x;
  int c = (lane < NE) ? cnt[lane] : 0;
  int nt = (c + BM - 1) / BM;
  int pre = nt;
#pragma unroll
  for (int d = 1; d < 32; d <<= 1) {
    int v = __shfl_up(pre, d, 64);
    if (lane >= d) pre += v;
  }
  int start = pre - nt;
  if (lane < NE) {
    for (int i = 0; i < nt; ++i) tile_hdr[1 + start + i] = (lane << 4) | i;
  }
  if (lane == NE - 1) tile_hdr[0] = pre;
}

// ---------------------------------------------------------------------------
// Kernel 2: single-matrix MFMA GEMM for gate OR up. Tile 192 x 256, K=2048.
// 1024 threads = 16 waves (4m x 4n); wave tile 48m x 64n (3mf x 4nf).
// nt weight loads (1 KB contiguous per row), distance-2 B reg slots,
// A double-buffer. grid = (2 mats x NF/256 = 8, MAXTILES).
// ---------------------------------------------------------------------------
__global__ __launch_bounds__(1024) void phase1_gu(
    const unsigned short* __restrict__ xb, const float* __restrict__ wg,
    const float* __restrict__ wu, const int* __restrict__ tile_hdr,
    const int* __restrict__ entries, const int* __restrict__ cnt,
    unsigned short* __restrict__ part) {
  const int s = blockIdx.y;
  if (s >= tile_hdr[0]) return;
  const int packed = tile_hdr[1 + s];
  const int e = packed >> 4, rt = packed & 15;
  const int n_e = cnt[e];
  const int mat = blockIdx.x & 1;
  const int f0 = (blockIdx.x >> 1) * BN;

  __shared__ unsigned short Bs[2][BN * BK];  // 2 x 32 KB, [n][k] swizzled
  __shared__ int pair_s[BM];

  const int tid = threadIdx.x;
  if (tid < BM) {
    int idx = rt * BM + tid;
    pair_s[tid] = (idx < n_e) ? entries[e * NT + idx] : -1;
  }
  __syncthreads();

  const int lane = tid & 63, wid = tid >> 6;          // wid 0..15
  const int wm = (wid >> 2) * 48, wn = (wid & 3) * 64;
  const int lm = lane & 15, lk = (lane >> 4) * 8;

  const unsigned short* aptr[3];
#pragma unroll
  for (int mf = 0; mf < 3; ++mf) {
    int p = pair_s[wm + mf * 16 + lm];
    int tok = (p >= 0) ? (p >> 2) : 0;
    aptr[mf] = xb + (size_t)tok * NH + lk;
  }

  // B staging: f-quad q = tid&63 (n = 4q..4q+3, 256 cols), k-quad g4.
  const int q = tid & 63, g4 = (tid >> 6) * 4;        // g4 covers 64 k
  const float* bp = (mat ? wu : wg) + (size_t)e * NH * NF + f0 + q * 4;

  float r0[4][4], r1[4][4];    // two named B slots (distance 2)
  short8 aC[3][2], aN[3][2];   // A double buffer

  f32x4 acc[3][4];
#pragma unroll
  for (int i = 0; i < 3; ++i)
#pragma unroll
    for (int j = 0; j < 4; ++j) acc[i][j] = (f32x4)(0.f);

  auto loadA = [&](int k0, short8 (&a)[3][2]) {
#pragma unroll
    for (int mf = 0; mf < 3; ++mf)
#pragma unroll
      for (int kc = 0; kc < 2; ++kc)
        a[mf][kc] = *reinterpret_cast<const short8*>(aptr[mf] + k0 + kc * 32);
  };
  auto loadB = [&](int k0, float (&r)[4][4]) {
#pragma unroll
    for (int i = 0; i < 4; ++i) {
      f32x4 v = __builtin_nontemporal_load(
          reinterpret_cast<const f32x4*>(bp + (size_t)(k0 + g4 + i) * NF));
      r[i][0] = v.x; r[i][1] = v.y; r[i][2] = v.z; r[i][3] = v.w;
    }
  };
  auto storeB = [&](const float (&r)[4][4], int b) {
#pragma unroll
    for (int j = 0; j < 4; ++j) {
      const int n = q * 4 + j;
      uint2 c0;
      c0.x = pkbf(r[0][j], r[1][j]); c0.y = pkbf(r[2][j], r[3][j]);
      *reinterpret_cast<uint2*>(&Bs[b][swz(n, g4)]) = c0;
    }
  };
  auto compute = [&](int c, const short8 (&a)[3][2]) {
#pragma unroll
    for (int kc = 0; kc < 2; ++kc) {
      short8 b2[4];
#pragma unroll
      for (int nf = 0; nf < 4; ++nf)
        b2[nf] = *reinterpret_cast<const short8*>(
            &Bs[c][swz(wn + nf * 16 + lm, kc * 32 + lk)]);
#pragma unroll
      for (int mf = 0; mf < 3; ++mf)
#pragma unroll
        for (int nf = 0; nf < 4; ++nf)
          acc[mf][nf] = __builtin_amdgcn_mfma_f32_16x16x32_bf16(a[mf][kc], b2[nf], acc[mf][nf], 0, 0, 0);
    }
  };

  const int NS = NH / BK;  // 32 (even)
  // prologue: A(0)->aC; B(0)->slot0->buf0; B(1)->slot1 in flight
  loadA(0, aC);
  loadB(0, r0);
  loadB(BK, r1);
  storeB(r0, 0);
  ASMV("s_waitcnt lgkmcnt(0)");
  __builtin_amdgcn_s_barrier();
  SCHED0();

  for (int t = 0; t < NS - 2; t += 2) {
    // even iter t: buf0, aC; slot1 holds B(t+1)
    loadA((t + 1) * BK, aN);
    SCHED0();
    loadB((t + 2) * BK, r0);
    SCHED0();
    compute(0, aC);
    SCHED0();
    storeB(r1, 1);
    ASMV("s_waitcnt lgkmcnt(0)");
    __builtin_amdgcn_s_barrier();
    SCHED0();
    // odd iter t+1: buf1, aN; slot0 holds B(t+2)
    loadA((t + 2) * BK, aC);
    SCHED0();
    loadB((t + 3) * BK, r1);
    SCHED0();
    compute(1, aN);
    SCHED0();
    storeB(r0, 0);
    ASMV("s_waitcnt lgkmcnt(0)");
    __builtin_amdgcn_s_barrier();
    SCHED0();
  }
  // tail: iters NS-2 (buf0, aC), NS-1 (buf1, aN); slot1 holds B(NS-1)
  loadA((NS - 1) * BK, aN);
  SCHED0();
  compute(0, aC);
  SCHED0();
  storeB(r1, 1);
  ASMV("s_waitcnt lgkmcnt(0)");
  __builtin_amdgcn_s_barrier();
  SCHED0();
  compute(1, aN);

  // epilogue: raw bf16 partials. D layout: col=lane&15, row=(lane>>4)*4+r.
  unsigned short* pout = part + (size_t)mat * NPAIR * NF;
  const int rbase = wm + (lane >> 4) * 4;
#pragma unroll
  for (int mf = 0; mf < 3; ++mf) {
#pragma unroll
    for (int r = 0; r < 4; ++r) {
      const int row = rbase + mf * 16 + r;
      const int p = pair_s[row];
      if (p < 0) continue;
#pragma unroll
      for (int nf = 0; nf < 4; ++nf)
        pout[(size_t)p * NF + f0 + wn + nf * 16 + lm] =
            (unsigned short)bfbits(acc[mf][nf][r]);
    }
  }
}

// ---------------------------------------------------------------------------
// Kernel 2b: act = silu(g) * u, streaming bf16. 4M elements, 8/thread.
// ---------------------------------------------------------------------------
__global__ __launch_bounds__(256) void act_combine(
    const unsigned short* __restrict__ part, unsigned short* __restrict__ act) {
  const size_t idx = ((size_t)blockIdx.x * 256 + threadIdx.x) * 8;
  uint4 gv = *reinterpret_cast<const uint4*>(part + idx);
  uint4 uv = *reinterpret_cast<const uint4*>(part + (size_t)NPAIR * NF + idx);
  const unsigned short* gs = reinterpret_cast<const unsigned short*>(&gv);
  const unsigned short* us = reinterpret_cast<const unsigned short*>(&uv);
  unsigned o[4];
#pragma unroll
  for (int j = 0; j < 4; ++j) {
    float g0 = bf2f(gs[2 * j]), g1 = bf2f(gs[2 * j + 1]);
    float u0 = bf2f(us[2 * j]), u1 = bf2f(us[2 * j + 1]);
    float o0 = (g0 / (1.f + __expf(-g0))) * u0;
    float o1 = (g1 / (1.f + __expf(-g1))) * u1;
    o[j] = pkbf(o0, o1);
  }
  *reinterpret_cast<uint4*>(act + idx) = make_uint4(o[0], o[1], o[2], o[3]);
}

// ---------------------------------------------------------------------------
// Kernel 3: down-proj MFMA GEMM. Tile 192 x 256, K=F=1024, 1024 threads.
// nt wd loads, distance-2 B, A double-buffer. Epilogue scales by w_tk[p],
// writes bf16 ypb. grid = (NH/256 = 8, MAXTILES).
// ---------------------------------------------------------------------------
__global__ __launch_bounds__(1024) void phase2_mfma(
    const unsigned short* __restrict__ act, const float* __restrict__ wd,
    const int* __restrict__ tile_hdr, const int* __restrict__ entries,
    const int* __restrict__ cnt, const float* __restrict__ w_tk,
    unsigned short* __restrict__ ypb) {
  const int s = blockIdx.y;
  if (s >= tile_hdr[0]) return;
  const int packed = tile_hdr[1 + s];
  const int e = packed >> 4, rt = packed & 15;
  const int n_e = cnt[e];
  const int h0 = blockIdx.x * BN;

  __shared__ unsigned short Bs[2][BN * BK];  // 2 x 32 KB
  __shared__ int pair_s[BM];

  const int tid = threadIdx.x;
  if (tid < BM) {
    int idx = rt * BM + tid;
    pair_s[tid] = (idx < n_e) ? entries[e * NT + idx] : -1;
  }
  __syncthreads();

  const int lane = tid & 63, wid = tid >> 6;
  const int wm = (wid >> 2) * 48, wn = (wid & 3) * 64;
  const int lm = lane & 15, lk = (lane >> 4) * 8;

  const unsigned short* aptr[3];
#pragma unroll
  for (int mf = 0; mf < 3; ++mf) {
    int p = pair_s[wm + mf * 16 + lm];
    int pa = (p >= 0) ? p : 0;
    aptr[mf] = act + (size_t)pa * NF + lk;
  }

  const int q = tid & 63, g4 = (tid >> 6) * 4;
  const float* bdp = wd + (size_t)e * NF * NH + h0 + q * 4;

  float r0[4][4], r1[4][4];
  short8 aC[3][2], aN[3][2];

  f32x4 acc[3][4];
#pragma unroll
  for (int i = 0; i < 3; ++i)
#pragma unroll
    for (int j = 0; j < 4; ++j) acc[i][j] = (f32x4)(0.f);

  auto loadA = [&](int k0, short8 (&a)[3][2]) {
#pragma unroll
    for (int mf = 0; mf < 3; ++mf)
#pragma unroll
      for (int kc = 0; kc < 2; ++kc)
        a[mf][kc] = *reinterpret_cast<const short8*>(aptr[mf] + k0 + kc * 32);
  };
  auto loadB = [&](int k0, float (&r)[4][4]) {
#pragma unroll
    for (int i = 0; i < 4; ++i) {
      f32x4 v = __builtin_nontemporal_load(
          reinterpret_cast<const f32x4*>(bdp + (size_t)(k0 + g4 + i) * NH));
      r[i][0] = v.x; r[i][1] = v.y; r[i][2] = v.z; r[i][3] = v.w;
    }
  };
  auto storeB = [&](const float (&r)[4][4], int b) {
#pragma unroll
    for (int j = 0; j < 4; ++j) {
      const int n = q * 4 + j;
      uint2 c0;
      c0.x = pkbf(r[0][j], r[1][j]); c0.y = pkbf(r[2][j], r[3][j]);
      *reinterpret_cast<uint2*>(&Bs[b][swz(n, g4)]) = c0;
    }
  };
  auto compute = [&](int c, const short8 (&a)[3][2]) {
#pragma unroll
    for (int kc = 0; kc < 2; ++kc) {
      short8 b2[4];
#pragma unroll
      for (int nf = 0; nf < 4; ++nf)
        b2[nf] = *reinterpret_cast<const short8*>(
            &Bs[c][swz(wn + nf * 16 + lm, kc * 32 + lk)]);
#pragma unroll
      for (int mf = 0; mf < 3; ++mf)
#pragma unroll
        for (int nf = 0; nf < 4; ++nf)
          acc[mf][nf] = __builtin_amdgcn_mfma_f32_16x16x32_bf16(a[mf][kc], b2[nf], acc[mf][nf], 0, 0, 0);
    }
  };

  const int NS = NF / BK;  // 16 (even)
  loadA(0, aC);
  loadB(0, r0);
  loadB(BK, r1);
  storeB(r0, 0);
  ASMV("s_waitcnt lgkmcnt(0)");
  __builtin_amdgcn_s_barrier();
  SCHED0();

  for (int t = 0; t < NS - 2; t += 2) {
    loadA((t + 1) * BK, aN);
    SCHED0();
    loadB((t + 2) * BK, r0);
    SCHED0();
    compute(0, aC);
    SCHED0();
    storeB(r1, 1);
    ASMV("s_waitcnt lgkmcnt(0)");
    __builtin_amdgcn_s_barrier();
    SCHED0();
    loadA((t + 2) * BK, aC);
    SCHED0();
    loadB((t + 3) * BK, r1);
    SCHED0();
    compute(1, aN);
    SCHED0();
    storeB(r0, 0);
    ASMV("s_waitcnt lgkmcnt(0)");
    __builtin_amdgcn_s_barrier();
    SCHED0();
  }
  loadA((NS - 1) * BK, aN);
  SCHED0();
  compute(0, aC);
  SCHED0();
  storeB(r1, 1);
  ASMV("s_waitcnt lgkmcnt(0)");
  __builtin_amdgcn_s_barrier();
  SCHED0();
  compute(1, aN);

  // epilogue: scale by routing weight, write bf16 ypb[p][h].
  const int rbase = wm + (lane >> 4) * 4;
#pragma unroll
  for (int mf = 0; mf < 3; ++mf) {
#pragma unroll
    for (int r = 0; r < 4; ++r) {
      const int row = rbase + mf * 16 + r;
      const int p = pair_s[row];
      if (p < 0) continue;
      const float w = w_tk[p];
#pragma unroll
      for (int nf = 0; nf < 4; ++nf)
        ypb[(size_t)p * NH + h0 + wn + nf * 16 + lm] =
            (unsigned short)bfbits(w * acc[mf][nf][r]);
    }
  }
}

// ---------------------------------------------------------------------------
// Kernel 4: combine. out[t,h] = sum_k ypb[t*4+k][h] (weights pre-applied).
// ---------------------------------------------------------------------------
__global__ __launch_bounds__(256) void combine_kernel(
    const unsigned short* __restrict__ ypb, float* __restrict__ out) {
  const size_t idx = (size_t)blockIdx.x * 256 + threadIdx.x;  // over NT*NH/8
  const int t = (int)(idx >> 8);
  const int h8 = (int)(idx & 255) * 8;
  float s[8] = {0, 0, 0, 0, 0, 0, 0, 0};
#pragma unroll
  for (int k = 0; k < NK; ++k) {
    uint4 v = *reinterpret_cast<const uint4*>(
        &ypb[((size_t)(t * NK + k)) * NH + h8]);
    const unsigned short* e = reinterpret_cast<const unsigned short*>(&v);
#pragma unroll
    for (int j = 0; j < 8; ++j) s[j] += bf2f(e[j]);
  }
  float4 o0 = make_float4(s[0], s[1], s[2], s[3]);
  float4 o1 = make_float4(s[4], s[5], s[6], s[7]);
  *reinterpret_cast<float4*>(&out[(size_t)t * NH + h8]) = o0;
  *reinterpret_cast<float4*>(&out[(size_t)t * NH + h8 + 4]) = o1;
}

// ---------------------------------------------------------------------------
extern "C" void kernel_launch(void* const* d_in, const int* in_sizes, int n_in,
                              void* d_out, int out_size, void* d_ws,
                              size_t ws_size, hipStream_t stream) {
  const float* x      = (const float*)d_in[0];
  const float* gate_w = (const float*)d_in[1];
  const float* wg     = (const float*)d_in[2];
  const float* wu     = (const float*)d_in[3];
  const float* wd     = (const float*)d_in[4];

  float* out        = (float*)d_out;
  float* logits_out = (float*)d_out + (size_t)NT * NH;

  char* ws = (char*)d_ws;
  int* cnt             = (int*)(ws + OFF_CNT);
  int* entries         = (int*)(ws + OFF_ENT);
  float* w_tk          = (float*)(ws + OFF_WTK);
  int* tile_hdr        = (int*)(ws + OFF_TIL);
  unsigned short* xb   = (unsigned short*)(ws + OFF_XB);
  unsigned short* act  = (unsigned short*)(ws + OFF_ACT);
  unsigned short* part = (unsigned short*)(ws + OFF_PART);
  unsigned short* ypb  = (unsigned short*)(ws + OFF_YPB);

  hipMemsetAsync(ws, 0, 1024, stream);  // zero expert counters

  router_kernel<<<NT, 256, 0, stream>>>(x, gate_w, logits_out, cnt, entries, w_tk, xb);
  build_tiles<<<1, 64, 0, stream>>>(cnt, tile_hdr);
  phase1_gu<<<dim3(2 * NF / BN, MAXTILES), 1024, 0, stream>>>(xb, wg, wu, tile_hdr, entries, cnt, part);
  act_combine<<<(NPAIR * NF / 8) / 256, 256, 0, stream>>>(part, act);
  phase2_mfma<<<dim3(NH / BN, MAXTILES), 1024, 0, stream>>>(act, wd, tile_hdr, entries, cnt, w_tk, ypb);
  combine_kernel<<<(NT * NH / 8) / 256, 256, 0, stream>>>(ypb, out);
}

// Round 21
// 280.584 us; speedup vs baseline: 2.2611x; 2.2611x over previous
//
#include <hip/hip_runtime.h>
#include <hip/hip_bf16.h>
#include <math.h>

// OLMoE sparse MoE block: E=32, K=4, H=2048, F=1024, T=1024 tokens.
// R18 configuration — verified 280.7 us. R19 (depth-3): flat. R20 (BN=256,
// 1024 thr): VGPR capped at 64 -> spill catastrophe. This is the practical
// optimum of the register/contiguity envelope.
#define NE 32
#define NK 4
#define NH 2048
#define NF 1024
#define NT 1024
#define NPAIR (NT * NK)

#define BM 192
#define BN 128
#define BK 64
#define MAXTILES 64

typedef __attribute__((ext_vector_type(8))) short short8;
typedef __attribute__((ext_vector_type(4))) float f32x4;

#define ASMV(s) asm volatile(s ::: "memory")
#define SCHED0() __builtin_amdgcn_sched_barrier(0)

// Workspace layout (bytes). part and ypb share OFF_YP region:
// part (16MB) is dead after act_combine; ypb (16MB) written by phase2 after.
static constexpr size_t OFF_CNT = 0;
static constexpr size_t OFF_ENT = 1024;
static constexpr size_t OFF_WTK = 1024 + 32 * 1024 * 4;
static constexpr size_t OFF_TIL = 200704;
static constexpr size_t OFF_XB  = 262144;                            // bf16 [1024][2048], 4MB
static constexpr size_t OFF_ACT = OFF_XB + (size_t)NT * NH * 2;      // bf16 [4096][1024], 8MB
static constexpr size_t OFF_YP  = OFF_ACT + (size_t)NPAIR * NF * 2;
static constexpr size_t OFF_PART = OFF_YP;                           // bf16 [2][4096][1024], 16MB
static constexpr size_t OFF_YPB  = OFF_YP + (size_t)2 * NPAIR * NF * 2;  // bf16 [4096][2048], 16MB

// ---------------------------------------------------------------------------
__device__ inline unsigned bfbits(float f) {
  return (unsigned)__builtin_bit_cast(unsigned short, __float2bfloat16(f));
}
__device__ inline unsigned pkbf(float lo, float hi) {
  return bfbits(lo) | (bfbits(hi) << 16);
}
__device__ inline float bf2f(unsigned short v) {
  unsigned u = ((unsigned)v) << 16;
  return __builtin_bit_cast(float, u);
}
// XOR-swizzled element index for a [rows][64] bf16 tile (row stride 128 B).
__device__ inline int swz(int r, int k) {
  int key = ((r & 7) ^ ((r >> 2) & 7)) & 7;
  int b = (r << 7) | (k << 1);
  return (b ^ (key << 4)) >> 1;
}

// ---------------------------------------------------------------------------
// Kernel 1: router (unchanged, validated).
// ---------------------------------------------------------------------------
__global__ __launch_bounds__(256) void router_kernel(
    const float* __restrict__ x, const float* __restrict__ gate_w,
    float* __restrict__ logits_out, int* __restrict__ cnt,
    int* __restrict__ entries, float* __restrict__ w_tk,
    unsigned short* __restrict__ xb) {
  __shared__ float xs[NH];
  __shared__ float logits_s[NE];
  const int t = blockIdx.x;
  const int tid = threadIdx.x;

  for (int i = tid; i < NH / 4; i += 256) {
    *reinterpret_cast<float4*>(&xs[i * 4]) =
        *reinterpret_cast<const float4*>(&x[(size_t)t * NH + i * 4]);
  }
  __syncthreads();

  {
    unsigned u[4];
#pragma unroll
    for (int j = 0; j < 4; ++j)
      u[j] = pkbf(xs[tid * 8 + 2 * j], xs[tid * 8 + 2 * j + 1]);
    *reinterpret_cast<uint4*>(&xb[(size_t)t * NH + tid * 8]) =
        make_uint4(u[0], u[1], u[2], u[3]);
  }

  const int wave = tid >> 6, lane = tid & 63;
  for (int ei = 0; ei < 8; ++ei) {
    const int e = wave * 8 + ei;
    const float* gw = gate_w + (size_t)e * NH;
    float s = 0.f;
    for (int h = lane; h < NH; h += 64) s += xs[h] * gw[h];
#pragma unroll
    for (int off = 32; off >= 1; off >>= 1) s += __shfl_xor(s, off, 64);
    if (lane == 0) logits_s[e] = s;
  }
  __syncthreads();

  if (wave == 0) {
    float v = (lane < NE) ? logits_s[lane] : -INFINITY;
    if (lane < NE) logits_out[(size_t)t * NE + lane] = v;
    float m = v;
#pragma unroll
    for (int off = 32; off >= 1; off >>= 1) m = fmaxf(m, __shfl_xor(m, off, 64));
    float ex = (lane < NE) ? expf(v - m) : 0.f;
    float sum = ex;
#pragma unroll
    for (int off = 32; off >= 1; off >>= 1) sum += __shfl_xor(sum, off, 64);
    float pv = (lane < NE) ? (ex / sum) : -1.f;
    for (int k = 0; k < NK; ++k) {
      float bv = pv;
      int bi = lane;
#pragma unroll
      for (int off = 32; off >= 1; off >>= 1) {
        float ov = __shfl_xor(bv, off, 64);
        int oi = __shfl_xor(bi, off, 64);
        if (ov > bv || (ov == bv && oi < bi)) { bv = ov; bi = oi; }
      }
      if (lane == 0) {
        int pos = atomicAdd(&cnt[bi], 1);
        entries[bi * NT + pos] = t * NK + k;
        w_tk[t * NK + k] = bv;
      }
      if (lane == bi) pv = -1.f;
    }
  }
}

// ---------------------------------------------------------------------------
// Kernel 1b: compact (expert, rowtile) tile table.
// ---------------------------------------------------------------------------
__global__ __launch_bounds__(64) void build_tiles(
    const int* __restrict__ cnt, int* __restrict__ tile_hdr) {
  const int lane = threadIdx.x;
  int c = (lane < NE) ? cnt[lane] : 0;
  int nt = (c + BM - 1) / BM;
  int pre = nt;
#pragma unroll
  for (int d = 1; d < 32; d <<= 1) {
    int v = __shfl_up(pre, d, 64);
    if (lane >= d) pre += v;
  }
  int start = pre - nt;
  if (lane < NE) {
    for (int i = 0; i < nt; ++i) tile_hdr[1 + start + i] = (lane << 4) | i;
  }
  if (lane == NE - 1) tile_hdr[0] = pre;
}

// ---------------------------------------------------------------------------
// Kernel 2: single-matrix MFMA GEMM for gate OR up. Tile 192 x 128, K=2048.
// nt weight loads, distance-2 B slots, and A DOUBLE-BUFFER (aC/aN): A(t+1)
// issued before compute(t) so the A-wait never exposes load latency.
// grid = (16, MAXTILES).
// ---------------------------------------------------------------------------
__global__ __launch_bounds__(512) void phase1_gu(
    const unsigned short* __restrict__ xb, const float* __restrict__ wg,
    const float* __restrict__ wu, const int* __restrict__ tile_hdr,
    const int* __restrict__ entries, const int* __restrict__ cnt,
    unsigned short* __restrict__ part) {
  const int s = blockIdx.y;
  if (s >= tile_hdr[0]) return;
  const int packed = tile_hdr[1 + s];
  const int e = packed >> 4, rt = packed & 15;
  const int n_e = cnt[e];
  const int mat = blockIdx.x & 1;
  const int f0 = (blockIdx.x >> 1) * BN;

  __shared__ unsigned short Bs[2][BN * BK];  // 2 x 16 KB, [n][k] swizzled
  __shared__ int pair_s[BM];

  const int tid = threadIdx.x;
  if (tid < BM) {
    int idx = rt * BM + tid;
    pair_s[tid] = (idx < n_e) ? entries[e * NT + idx] : -1;
  }
  __syncthreads();

  const int lane = tid & 63, wid = tid >> 6;
  const int wm = (wid >> 1) * 48, wn = (wid & 1) * 64;
  const int lm = lane & 15, lk = (lane >> 4) * 8;

  const unsigned short* aptr[3];
#pragma unroll
  for (int mf = 0; mf < 3; ++mf) {
    int p = pair_s[wm + mf * 16 + lm];
    int tok = (p >= 0) ? (p >> 2) : 0;
    aptr[mf] = xb + (size_t)tok * NH + lk;
  }

  const int q = tid & 31, g4 = (tid >> 5) * 4;
  const float* bp = (mat ? wu : wg) + (size_t)e * NH * NF + f0 + q * 4;

  float r0[4][4], r1[4][4];    // two named B slots (distance 2)
  short8 aC[3][2], aN[3][2];   // A double buffer

  f32x4 acc[3][4];
#pragma unroll
  for (int i = 0; i < 3; ++i)
#pragma unroll
    for (int j = 0; j < 4; ++j) acc[i][j] = (f32x4)(0.f);

  auto loadA = [&](int k0, short8 (&a)[3][2]) {
#pragma unroll
    for (int mf = 0; mf < 3; ++mf)
#pragma unroll
      for (int kc = 0; kc < 2; ++kc)
        a[mf][kc] = *reinterpret_cast<const short8*>(aptr[mf] + k0 + kc * 32);
  };
  auto loadB = [&](int k0, float (&r)[4][4]) {
#pragma unroll
    for (int i = 0; i < 4; ++i) {
      f32x4 v = __builtin_nontemporal_load(
          reinterpret_cast<const f32x4*>(bp + (size_t)(k0 + g4 + i) * NF));
      r[i][0] = v.x; r[i][1] = v.y; r[i][2] = v.z; r[i][3] = v.w;
    }
  };
  auto storeB = [&](const float (&r)[4][4], int b) {
#pragma unroll
    for (int j = 0; j < 4; ++j) {
      const int n = q * 4 + j;
      uint2 c0;
      c0.x = pkbf(r[0][j], r[1][j]); c0.y = pkbf(r[2][j], r[3][j]);
      *reinterpret_cast<uint2*>(&Bs[b][swz(n, g4)]) = c0;
    }
  };
  auto compute = [&](int c, const short8 (&a)[3][2]) {
#pragma unroll
    for (int kc = 0; kc < 2; ++kc) {
      short8 b2[4];
#pragma unroll
      for (int nf = 0; nf < 4; ++nf)
        b2[nf] = *reinterpret_cast<const short8*>(
            &Bs[c][swz(wn + nf * 16 + lm, kc * 32 + lk)]);
#pragma unroll
      for (int mf = 0; mf < 3; ++mf)
#pragma unroll
        for (int nf = 0; nf < 4; ++nf)
          acc[mf][nf] = __builtin_amdgcn_mfma_f32_16x16x32_bf16(a[mf][kc], b2[nf], acc[mf][nf], 0, 0, 0);
    }
  };

  const int NS = NH / BK;  // 32 (even)
  // prologue: A(0)->aC; B(0)->slot0->buf0; B(1)->slot1 in flight
  loadA(0, aC);
  loadB(0, r0);
  loadB(BK, r1);
  storeB(r0, 0);
  ASMV("s_waitcnt lgkmcnt(0)");
  __builtin_amdgcn_s_barrier();
  SCHED0();

  for (int t = 0; t < NS - 2; t += 2) {
    // even iter t: buf0, aC; slot1 holds B(t+1)
    loadA((t + 1) * BK, aN);
    SCHED0();
    loadB((t + 2) * BK, r0);
    SCHED0();
    compute(0, aC);                 // aC issued last iter -> no latency
    SCHED0();
    storeB(r1, 1);
    ASMV("s_waitcnt lgkmcnt(0)");
    __builtin_amdgcn_s_barrier();
    SCHED0();
    // odd iter t+1: buf1, aN; slot0 holds B(t+2)
    loadA((t + 2) * BK, aC);
    SCHED0();
    loadB((t + 3) * BK, r1);
    SCHED0();
    compute(1, aN);
    SCHED0();
    storeB(r0, 0);
    ASMV("s_waitcnt lgkmcnt(0)");
    __builtin_amdgcn_s_barrier();
    SCHED0();
  }
  // tail: iters NS-2 (buf0, aC), NS-1 (buf1, aN); slot1 holds B(NS-1)
  loadA((NS - 1) * BK, aN);
  SCHED0();
  compute(0, aC);
  SCHED0();
  storeB(r1, 1);
  ASMV("s_waitcnt lgkmcnt(0)");
  __builtin_amdgcn_s_barrier();
  SCHED0();
  compute(1, aN);

  // epilogue: raw bf16 partials. D layout: col=lane&15, row=(lane>>4)*4+r.
  unsigned short* pout = part + (size_t)mat * NPAIR * NF;
  const int rbase = wm + (lane >> 4) * 4;
#pragma unroll
  for (int mf = 0; mf < 3; ++mf) {
#pragma unroll
    for (int r = 0; r < 4; ++r) {
      const int row = rbase + mf * 16 + r;
      const int p = pair_s[row];
      if (p < 0) continue;
#pragma unroll
      for (int nf = 0; nf < 4; ++nf)
        pout[(size_t)p * NF + f0 + wn + nf * 16 + lm] =
            (unsigned short)bfbits(acc[mf][nf][r]);
    }
  }
}

// ---------------------------------------------------------------------------
// Kernel 2b: act = silu(g) * u, streaming bf16. 4M elements, 8/thread.
// ---------------------------------------------------------------------------
__global__ __launch_bounds__(256) void act_combine(
    const unsigned short* __restrict__ part, unsigned short* __restrict__ act) {
  const size_t idx = ((size_t)blockIdx.x * 256 + threadIdx.x) * 8;
  uint4 gv = *reinterpret_cast<const uint4*>(part + idx);
  uint4 uv = *reinterpret_cast<const uint4*>(part + (size_t)NPAIR * NF + idx);
  const unsigned short* gs = reinterpret_cast<const unsigned short*>(&gv);
  const unsigned short* us = reinterpret_cast<const unsigned short*>(&uv);
  unsigned o[4];
#pragma unroll
  for (int j = 0; j < 4; ++j) {
    float g0 = bf2f(gs[2 * j]), g1 = bf2f(gs[2 * j + 1]);
    float u0 = bf2f(us[2 * j]), u1 = bf2f(us[2 * j + 1]);
    float o0 = (g0 / (1.f + __expf(-g0))) * u0;
    float o1 = (g1 / (1.f + __expf(-g1))) * u1;
    o[j] = pkbf(o0, o1);
  }
  *reinterpret_cast<uint4*>(act + idx) = make_uint4(o[0], o[1], o[2], o[3]);
}

// ---------------------------------------------------------------------------
// Kernel 3: down-proj MFMA GEMM. nt wd loads, distance-2 B, A double-buffer.
// Epilogue scales by w_tk[p] and writes bf16 ypb. grid = (16, MAXTILES).
// ---------------------------------------------------------------------------
__global__ __launch_bounds__(512) void phase2_mfma(
    const unsigned short* __restrict__ act, const float* __restrict__ wd,
    const int* __restrict__ tile_hdr, const int* __restrict__ entries,
    const int* __restrict__ cnt, const float* __restrict__ w_tk,
    unsigned short* __restrict__ ypb) {
  const int s = blockIdx.y;
  if (s >= tile_hdr[0]) return;
  const int packed = tile_hdr[1 + s];
  const int e = packed >> 4, rt = packed & 15;
  const int n_e = cnt[e];
  const int h0 = blockIdx.x * BN;

  __shared__ unsigned short Bs[2][BN * BK];  // 2 x 16 KB
  __shared__ int pair_s[BM];

  const int tid = threadIdx.x;
  if (tid < BM) {
    int idx = rt * BM + tid;
    pair_s[tid] = (idx < n_e) ? entries[e * NT + idx] : -1;
  }
  __syncthreads();

  const int lane = tid & 63, wid = tid >> 6;
  const int wm = (wid >> 1) * 48, wn = (wid & 1) * 64;
  const int lm = lane & 15, lk = (lane >> 4) * 8;

  const unsigned short* aptr[3];
#pragma unroll
  for (int mf = 0; mf < 3; ++mf) {
    int p = pair_s[wm + mf * 16 + lm];
    int pa = (p >= 0) ? p : 0;
    aptr[mf] = act + (size_t)pa * NF + lk;
  }

  const int q = tid & 31, g4 = (tid >> 5) * 4;
  const float* bdp = wd + (size_t)e * NF * NH + h0 + q * 4;

  float r0[4][4], r1[4][4];
  short8 aC[3][2], aN[3][2];

  f32x4 acc[3][4];
#pragma unroll
  for (int i = 0; i < 3; ++i)
#pragma unroll
    for (int j = 0; j < 4; ++j) acc[i][j] = (f32x4)(0.f);

  auto loadA = [&](int k0, short8 (&a)[3][2]) {
#pragma unroll
    for (int mf = 0; mf < 3; ++mf)
#pragma unroll
      for (int kc = 0; kc < 2; ++kc)
        a[mf][kc] = *reinterpret_cast<const short8*>(aptr[mf] + k0 + kc * 32);
  };
  auto loadB = [&](int k0, float (&r)[4][4]) {
#pragma unroll
    for (int i = 0; i < 4; ++i) {
      f32x4 v = __builtin_nontemporal_load(
          reinterpret_cast<const f32x4*>(bdp + (size_t)(k0 + g4 + i) * NH));
      r[i][0] = v.x; r[i][1] = v.y; r[i][2] = v.z; r[i][3] = v.w;
    }
  };
  auto storeB = [&](const float (&r)[4][4], int b) {
#pragma unroll
    for (int j = 0; j < 4; ++j) {
      const int n = q * 4 + j;
      uint2 c0;
      c0.x = pkbf(r[0][j], r[1][j]); c0.y = pkbf(r[2][j], r[3][j]);
      *reinterpret_cast<uint2*>(&Bs[b][swz(n, g4)]) = c0;
    }
  };
  auto compute = [&](int c, const short8 (&a)[3][2]) {
#pragma unroll
    for (int kc = 0; kc < 2; ++kc) {
      short8 b2[4];
#pragma unroll
      for (int nf = 0; nf < 4; ++nf)
        b2[nf] = *reinterpret_cast<const short8*>(
            &Bs[c][swz(wn + nf * 16 + lm, kc * 32 + lk)]);
#pragma unroll
      for (int mf = 0; mf < 3; ++mf)
#pragma unroll
        for (int nf = 0; nf < 4; ++nf)
          acc[mf][nf] = __builtin_amdgcn_mfma_f32_16x16x32_bf16(a[mf][kc], b2[nf], acc[mf][nf], 0, 0, 0);
    }
  };

  const int NS = NF / BK;  // 16 (even)
  loadA(0, aC);
  loadB(0, r0);
  loadB(BK, r1);
  storeB(r0, 0);
  ASMV("s_waitcnt lgkmcnt(0)");
  __builtin_amdgcn_s_barrier();
  SCHED0();

  for (int t = 0; t < NS - 2; t += 2) {
    loadA((t + 1) * BK, aN);
    SCHED0();
    loadB((t + 2) * BK, r0);
    SCHED0();
    compute(0, aC);
    SCHED0();
    storeB(r1, 1);
    ASMV("s_waitcnt lgkmcnt(0)");
    __builtin_amdgcn_s_barrier();
    SCHED0();
    loadA((t + 2) * BK, aC);
    SCHED0();
    loadB((t + 3) * BK, r1);
    SCHED0();
    compute(1, aN);
    SCHED0();
    storeB(r0, 0);
    ASMV("s_waitcnt lgkmcnt(0)");
    __builtin_amdgcn_s_barrier();
    SCHED0();
  }
  loadA((NS - 1) * BK, aN);
  SCHED0();
  compute(0, aC);
  SCHED0();
  storeB(r1, 1);
  ASMV("s_waitcnt lgkmcnt(0)");
  __builtin_amdgcn_s_barrier();
  SCHED0();
  compute(1, aN);

  // epilogue: scale by routing weight, write bf16 ypb[p][h].
  const int rbase = wm + (lane >> 4) * 4;
#pragma unroll
  for (int mf = 0; mf < 3; ++mf) {
#pragma unroll
    for (int r = 0; r < 4; ++r) {
      const int row = rbase + mf * 16 + r;
      const int p = pair_s[row];
      if (p < 0) continue;
      const float w = w_tk[p];
#pragma unroll
      for (int nf = 0; nf < 4; ++nf)
        ypb[(size_t)p * NH + h0 + wn + nf * 16 + lm] =
            (unsigned short)bfbits(w * acc[mf][nf][r]);
    }
  }
}

// ---------------------------------------------------------------------------
// Kernel 4: combine. out[t,h] = sum_k ypb[t*4+k][h] (weights pre-applied).
// ---------------------------------------------------------------------------
__global__ __launch_bounds__(256) void combine_kernel(
    const unsigned short* __restrict__ ypb, float* __restrict__ out) {
  const size_t idx = (size_t)blockIdx.x * 256 + threadIdx.x;  // over NT*NH/8
  const int t = (int)(idx >> 8);
  const int h8 = (int)(idx & 255) * 8;
  float s[8] = {0, 0, 0, 0, 0, 0, 0, 0};
#pragma unroll
  for (int k = 0; k < NK; ++k) {
    uint4 v = *reinterpret_cast<const uint4*>(
        &ypb[((size_t)(t * NK + k)) * NH + h8]);
    const unsigned short* e = reinterpret_cast<const unsigned short*>(&v);
#pragma unroll
    for (int j = 0; j < 8; ++j) s[j] += bf2f(e[j]);
  }
  float4 o0 = make_float4(s[0], s[1], s[2], s[3]);
  float4 o1 = make_float4(s[4], s[5], s[6], s[7]);
  *reinterpret_cast<float4*>(&out[(size_t)t * NH + h8]) = o0;
  *reinterpret_cast<float4*>(&out[(size_t)t * NH + h8 + 4]) = o1;
}

// ---------------------------------------------------------------------------
extern "C" void kernel_launch(void* const* d_in, const int* in_sizes, int n_in,
                              void* d_out, int out_size, void* d_ws,
                              size_t ws_size, hipStream_t stream) {
  const float* x      = (const float*)d_in[0];
  const float* gate_w = (const float*)d_in[1];
  const float* wg     = (const float*)d_in[2];
  const float* wu     = (const float*)d_in[3];
  const float* wd     = (const float*)d_in[4];

  float* out        = (float*)d_out;
  float* logits_out = (float*)d_out + (size_t)NT * NH;

  char* ws = (char*)d_ws;
  int* cnt             = (int*)(ws + OFF_CNT);
  int* entries         = (int*)(ws + OFF_ENT);
  float* w_tk          = (float*)(ws + OFF_WTK);
  int* tile_hdr        = (int*)(ws + OFF_TIL);
  unsigned short* xb   = (unsigned short*)(ws + OFF_XB);
  unsigned short* act  = (unsigned short*)(ws + OFF_ACT);
  unsigned short* part = (unsigned short*)(ws + OFF_PART);
  unsigned short* ypb  = (unsigned short*)(ws + OFF_YPB);

  hipMemsetAsync(ws, 0, 1024, stream);  // zero expert counters

  router_kernel<<<NT, 256, 0, stream>>>(x, gate_w, logits_out, cnt, entries, w_tk, xb);
  build_tiles<<<1, 64, 0, stream>>>(cnt, tile_hdr);
  phase1_gu<<<dim3(16, MAXTILES), 512, 0, stream>>>(xb, wg, wu, tile_hdr, entries, cnt, part);
  act_combine<<<(NPAIR * NF / 8) / 256, 256, 0, stream>>>(part, act);
  phase2_mfma<<<dim3(NH / BN, MAXTILES), 512, 0, stream>>>(act, wd, tile_hdr, entries, cnt, w_tk, ypb);
  combine_kernel<<<(NT * NH / 8) / 256, 256, 0, stream>>>(ypb, out);
}